// Round 4
// baseline (1715.670 us; speedup 1.0000x reference)
//
#include <hip/hip_runtime.h>
#include <stdint.h>

#define T_STEPS 14
#define B_DIM   4096
#define I_DIM   2048
#define H_DIM   1024
#define O_DIM   128
#define K_TOT   3072   // I_DIM + H_DIM
#define ZBYTES  ((size_t)B_DIM * H_DIM)

// fixed-point scale 2^25: |w|max ~0.16 -> |W| ~5.1M, 3 signed base-256 digits exact
#define WSCALE_F 33554432.0f

typedef __bf16  bf16x8  __attribute__((ext_vector_type(8)));
typedef float   floatx4 __attribute__((ext_vector_type(4)));
typedef int     int4v   __attribute__((ext_vector_type(4)));
typedef int     int16v  __attribute__((ext_vector_type(16)));
typedef unsigned long long u64;

__device__ __forceinline__ uint16_t f2bf_rne(float f) {
    uint32_t u = __float_as_uint(f);
    u += 0x7fffu + ((u >> 16) & 1u);
    return (uint16_t)(u >> 16);
}
__device__ __forceinline__ float bf2f(uint16_t h) {
    return __uint_as_float(((uint32_t)h) << 16);
}

// async global->LDS, 16B/lane; LDS dest = wave-uniform base + lane*16 (implicit)
__device__ __forceinline__ void gload_lds16(const void* g, void* l) {
    __builtin_amdgcn_global_load_lds((__attribute__((address_space(1))) void*)g,
                                     (__attribute__((address_space(3))) void*)l, 16, 0, 0);
}

// coherent 16B read of z spikes: agent-scope relaxed atomics (2x8B) bypass the
// non-coherent per-XCD L2 -> correct on every graph replay (no stale-line hazard)
__device__ __forceinline__ int4v zload16(const int8_t* p) {
    union { u64 q[2]; int4v v; } u;
    u.q[0] = __hip_atomic_load((u64*)(p),     __ATOMIC_RELAXED, __HIP_MEMORY_SCOPE_AGENT);
    u.q[1] = __hip_atomic_load((u64*)(p + 8), __ATOMIC_RELAXED, __HIP_MEMORY_SCOPE_AGENT);
    return u.v;
}

// ================= fragment-order layouts, BK=128 (validated r11) =================
// B digits: WB[nt(32)][ktw(24)][s(3)][kk(4)][lane(64)][16B]      (12 KB chunks)
// A spikes: Xall[t][mIdx(32)][ktx(16)][group(4)][kk(4)][lane(64)][16B]  (16 KB chunks)
// Z state:  ZS[t][mIdx(32)][ktz(8)][group(4)][kk(4)][lane(64)][16B]     (16 KB chunks)
// element (row = group*32 + (lane&31), k = kt*128 + kk*32 + (lane>>5)*16 + j)

__global__ void split_w_kernel(const float* __restrict__ w_in, const float* __restrict__ w_rec,
                               int8_t* __restrict__ WB) {
    int idx = blockIdx.x * 256 + threadIdx.x;          // over H_DIM*K_TOT
    int h = idx / K_TOT;
    int k = idx - h * K_TOT;
    float w = (k < I_DIM) ? w_in[(size_t)h * I_DIM + k]
                          : w_rec[(size_t)h * H_DIM + (k - I_DIM)];
    int W  = __float2int_rn(w * WSCALE_F);
    int d0 = (int8_t)(W & 0xFF);
    int r1 = (W - d0) >> 8;
    int d1 = (int8_t)(r1 & 0xFF);
    int d2 = (r1 - d1) >> 8;                           // |d2| <= ~80
    int nt = h >> 5, n32 = h & 31;
    int ktw = k >> 7, k128 = k & 127;
    int kk = k128 >> 5, half = (k128 >> 4) & 1, j = k128 & 15;
    int lane = half * 32 + n32;
    size_t base = (size_t)(nt * 24 + ktw) * 12288 + kk * 1024 + lane * 16 + j;
    WB[base] = (int8_t)d0; WB[base + 4096] = (int8_t)d1; WB[base + 8192] = (int8_t)d2;
}

// ---------- out_w -> bf16 hi/mid/lo (validated) ----------
__global__ void split_ow_kernel(const float* __restrict__ out_w, uint16_t* __restrict__ OW3) {
    int idx = blockIdx.x * 256 + threadIdx.x;          // over O_DIM*H_DIM
    float w = out_w[idx];
    uint16_t hi = f2bf_rne(w);
    float r1 = w - bf2f(hi);
    uint16_t mid = f2bf_rne(r1);
    float r2 = r1 - bf2f(mid);
    uint16_t lo = f2bf_rne(r2);
    const size_t S = (size_t)O_DIM * H_DIM;
    OW3[idx] = hi; OW3[idx + S] = mid; OW3[idx + 2 * S] = lo;
}

// ---------- x fp32 -> i8, ALL timesteps, BK=128 fragment-order (validated r11) ----------
__global__ void cvt_x_kernel(const float* __restrict__ x, int8_t* __restrict__ xb) {
    size_t gid = (size_t)blockIdx.x * 256 + threadIdx.x;   // one 16B output granule each
    int g = (int)(gid & 1023);                             // granule within 16KB chunk
    size_t chunk = gid >> 10;                              // (t*32 + mIdx)*16 + kt
    int kt   = (int)(chunk & 15);
    int mIdx = (int)((chunk >> 4) & 31);
    int t    = (int)(chunk >> 9);
    int group = g >> 8, kk = (g >> 6) & 3, lane = g & 63;
    int half = lane >> 5, row32 = lane & 31;
    int b = mIdx * 128 + group * 32 + row32;
    int k = kt * 128 + kk * 32 + half * 16;
    const float4* src = (const float4*)(x + ((size_t)t * B_DIM + b) * I_DIM + k);
    union { int8_t bytes[16]; int4v v; } u;
#pragma unroll
    for (int q = 0; q < 4; ++q) {
        float4 f = src[q];
        u.bytes[q * 4 + 0] = (int8_t)(f.x > 0.5f);
        u.bytes[q * 4 + 1] = (int8_t)(f.y > 0.5f);
        u.bytes[q * 4 + 2] = (int8_t)(f.z > 0.5f);
        u.bytes[q * 4 + 3] = (int8_t)(f.w > 0.5f);
    }
    ((int4v*)xb)[gid] = u.v;
}

// ---------- zero the group-sync counters (32 groups x 13 steps x 128B stride) ----------
// agent-scope stores: zeros reach the coherence point regardless of replay history
__global__ void zero_cnt_kernel(uint32_t* __restrict__ cnt) {
    __hip_atomic_store(&cnt[blockIdx.x * 256 + threadIdx.x], 0u,
                       __ATOMIC_RELAXED, __HIP_MEMORY_SCOPE_AGENT);
}

// ================= pipelined K-step (validated R2/R3) =================
// A fragments: global->VGPR direct (read by one lane of one wave only). B (weights,
// reused 4x/block) double-buffered in LDS with counted vmcnt: per iter the vmem ops
// issued are [A-loads][stageB(kt+1):3]; the counted wait drains B(kt) (issued last
// iter) while keeping this iter's loads in flight across the raw s_barrier.
__device__ __forceinline__ void lif_iter(const int8_t* __restrict__ aP,   // A frag: chunk + wave*4096 + lane*16
                                         const int8_t* __restrict__ bPn,  // next B chunk (12KB) or null
                                         const int8_t* cur, int8_t* nxt,  // LDS ping-pong
                                         int wave, int lane, bool stage_next,
                                         int16v (&acc)[3]) {
    int4v a0 = *(const int4v*)(aP);
    int4v a1 = *(const int4v*)(aP + 1024);
    int4v a2 = *(const int4v*)(aP + 2048);
    int4v a3 = *(const int4v*)(aP + 3072);
    __builtin_amdgcn_sched_barrier(0);
    if (stage_next) {
        gload_lds16(bPn + (size_t)wave * 1024 + lane * 16,       nxt + wave * 1024);
        gload_lds16(bPn + (size_t)(4 + wave) * 1024 + lane * 16, nxt + (4 + wave) * 1024);
        gload_lds16(bPn + (size_t)(8 + wave) * 1024 + lane * 16, nxt + (8 + wave) * 1024);
        asm volatile("s_waitcnt vmcnt(7)" ::: "memory");   // drain B(kt); keep A(kt)+B(kt+1) in flight
    } else {
        asm volatile("s_waitcnt vmcnt(4)" ::: "memory");   // last iter: drain B(kt)
    }
    __builtin_amdgcn_s_barrier();                          // all waves' B(kt) landed
    __builtin_amdgcn_sched_barrier(0);
#pragma unroll
    for (int kk = 0; kk < 4; ++kk) {
        int4v aF = (kk == 0) ? a0 : (kk == 1) ? a1 : (kk == 2) ? a2 : a3;
#pragma unroll
        for (int s = 0; s < 3; ++s) {
            int4v bF = *(const int4v*)(cur + s * 4096 + kk * 1024 + lane * 16);
            acc[s] = __builtin_amdgcn_mfma_i32_32x32x32_i8(aF, bF, acc[s], 0, 0, 0);
        }
    }
    asm volatile("s_waitcnt lgkmcnt(0)" ::: "memory");     // reads of 'cur' done
    __builtin_amdgcn_s_barrier();                          // safe to overwrite 'cur' next iter
}

// z-phase variant: A via coherent atomic 8B loads (8 loads) -> vmcnt counts shift to 11/8
__device__ __forceinline__ void lif_iter_z(const int8_t* __restrict__ aP,
                                           const int8_t* __restrict__ bPn,
                                           const int8_t* cur, int8_t* nxt,
                                           int wave, int lane, bool stage_next,
                                           int16v (&acc)[3]) {
    int4v a0 = zload16(aP);
    int4v a1 = zload16(aP + 1024);
    int4v a2 = zload16(aP + 2048);
    int4v a3 = zload16(aP + 3072);
    __builtin_amdgcn_sched_barrier(0);
    if (stage_next) {
        gload_lds16(bPn + (size_t)wave * 1024 + lane * 16,       nxt + wave * 1024);
        gload_lds16(bPn + (size_t)(4 + wave) * 1024 + lane * 16, nxt + (4 + wave) * 1024);
        gload_lds16(bPn + (size_t)(8 + wave) * 1024 + lane * 16, nxt + (8 + wave) * 1024);
        asm volatile("s_waitcnt vmcnt(11)" ::: "memory");  // drain B(kt); keep 8 z + 3 B(kt+1) in flight
    } else {
        asm volatile("s_waitcnt vmcnt(8)" ::: "memory");   // last iter: drain B(kt)
    }
    __builtin_amdgcn_s_barrier();
    __builtin_amdgcn_sched_barrier(0);
#pragma unroll
    for (int kk = 0; kk < 4; ++kk) {
        int4v aF = (kk == 0) ? a0 : (kk == 1) ? a1 : (kk == 2) ? a2 : a3;
#pragma unroll
        for (int s = 0; s < 3; ++s) {
            int4v bF = *(const int4v*)(cur + s * 4096 + kk * 1024 + lane * 16);
            acc[s] = __builtin_amdgcn_mfma_i32_32x32x32_i8(aF, bF, acc[s], 0, 0, 0);
        }
    }
    asm volatile("s_waitcnt lgkmcnt(0)" ::: "memory");
    __builtin_amdgcn_s_barrier();
}

template<int NKT>
__device__ __forceinline__ void run_phase(const int8_t* __restrict__ aChunk0,  // + kt*16384
                                          const int8_t* __restrict__ bChunk0,  // + kt*12288
                                          int8_t* sB0, int8_t* sB1,
                                          int wave, int lane, int16v (&acc)[3]) {
    gload_lds16(bChunk0 + (size_t)wave * 1024 + lane * 16,       sB0 + wave * 1024);
    gload_lds16(bChunk0 + (size_t)(4 + wave) * 1024 + lane * 16, sB0 + (4 + wave) * 1024);
    gload_lds16(bChunk0 + (size_t)(8 + wave) * 1024 + lane * 16, sB0 + (8 + wave) * 1024);
    const int8_t* aW = aChunk0 + wave * 4096 + lane * 16;
#pragma unroll 1
    for (int kt = 0; kt + 2 < NKT; kt += 2) {
        lif_iter(aW + (size_t)kt * 16384,       bChunk0 + (size_t)(kt + 1) * 12288, sB0, sB1, wave, lane, true, acc);
        lif_iter(aW + (size_t)(kt + 1) * 16384, bChunk0 + (size_t)(kt + 2) * 12288, sB1, sB0, wave, lane, true, acc);
    }
    lif_iter(aW + (size_t)(NKT - 2) * 16384, bChunk0 + (size_t)(NKT - 1) * 12288, sB0, sB1, wave, lane, true, acc);
    lif_iter(aW + (size_t)(NKT - 1) * 16384, nullptr,                             sB1, sB0, wave, lane, false, acc);
}

template<int NKT>
__device__ __forceinline__ void run_phase_z(const int8_t* __restrict__ aChunk0,
                                            const int8_t* __restrict__ bChunk0,
                                            int8_t* sB0, int8_t* sB1,
                                            int wave, int lane, int16v (&acc)[3]) {
    gload_lds16(bChunk0 + (size_t)wave * 1024 + lane * 16,       sB0 + wave * 1024);
    gload_lds16(bChunk0 + (size_t)(4 + wave) * 1024 + lane * 16, sB0 + (4 + wave) * 1024);
    gload_lds16(bChunk0 + (size_t)(8 + wave) * 1024 + lane * 16, sB0 + (8 + wave) * 1024);
    const int8_t* aW = aChunk0 + wave * 4096 + lane * 16;
#pragma unroll 1
    for (int kt = 0; kt + 2 < NKT; kt += 2) {
        lif_iter_z(aW + (size_t)kt * 16384,       bChunk0 + (size_t)(kt + 1) * 12288, sB0, sB1, wave, lane, true, acc);
        lif_iter_z(aW + (size_t)(kt + 1) * 16384, bChunk0 + (size_t)(kt + 2) * 12288, sB1, sB0, wave, lane, true, acc);
    }
    lif_iter_z(aW + (size_t)(NKT - 2) * 16384, bChunk0 + (size_t)(NKT - 1) * 12288, sB0, sB1, wave, lane, true, acc);
    lif_iter_z(aW + (size_t)(NKT - 1) * 16384, nullptr,                             sB1, sB0, wave, lane, false, acc);
}

// ================= persistent LIF: all 14 steps, ONE PLAIN launch =================
// PLAIN launch (graph-capture-safe; hipLaunchCooperativeKernel is NOT capturable and
// silently diverted R1-R3 benches to the slow fallback). Co-residency of all 1024
// blocks is by exact-fit capacity: 64 VGPR (<=128 bound), 28KB LDS x4 = 112KB <= 160KB,
// 16 waves/CU <= 32 -> 4 blocks/CU x 256 CU = 1024 = grid. (The coop launch's own
// residency check passing in R1-R3 validated this arithmetic on hardware.)
// - v,i state in VGPRs the whole simulation.
// - Cross-block dep is mIdx-group-local (32 blocks): flag sync; spin loads relaxed
//   agent-scope (no L2 invalidates -> W stays cached, groups drift freely).
// - z(t): producers store relaxed agent-scope 8B (write-through to coherence point);
//   __syncthreads drains vmcnt; flag fetch_add is RELEASE (closes the store-queue vs
//   flag race). Consumers read z via agent-scope atomic loads (replay-safe).
__launch_bounds__(256, 4)
__global__ void lif_persist_kernel(const int8_t* __restrict__ Xall,
                                   const int8_t* __restrict__ WB,
                                   int8_t* __restrict__ ZS,      // 13 per-step z buffers
                                   uint16_t* __restrict__ Zbf,
                                   uint32_t* __restrict__ cnt) {
    __shared__ int8_t sB0[12288];   // [s(3)][kk(4)][lane(64)][16B]
    __shared__ int8_t sB1[12288];
    __shared__ int8_t sZ[4096];     // z repack staging

    const int tid  = threadIdx.x;
    const int wave = tid >> 6, lane = tid & 63;
    const int lane32 = lane & 31, hl = lane >> 5;

    // 2D parity swizzle (bijective on 0..1023; correctness-independent of XCD mapping)
    const int bid = blockIdx.x;
    const int xs = bid & 7, q = bid >> 3;
    const int mIdx = (xs & 1) * 16 + (q & 15);
    const int nt   = (xs >> 1) * 8 + (q >> 4);

    const int mBase = mIdx * 128, nBase = nt * 32;
    const int8_t* wbStrip = WB + (size_t)nt * 24 * 12288;

    float vmem[16], isyn[16];
#pragma unroll
    for (int r = 0; r < 16; ++r) { vmem[r] = 0.0f; isyn[r] = 0.0f; }

    for (int t = 0; t < T_STEPS; ++t) {
        int16v acc[3] = {};

        // ---- X phase: kt 0..15 (no dependence on z(t-1)) ----
        const int8_t* Xt = Xall + (size_t)t * ((size_t)B_DIM * I_DIM) + (size_t)mIdx * 16 * 16384;
        run_phase<16>(Xt, wbStrip, sB0, sB1, wave, lane, acc);

        // ---- recurrent phase: needs z(t-1) from the 32 blocks of this mIdx group ----
        if (t > 0) {
            if (tid == 0) {
                const uint32_t* f = cnt + ((size_t)mIdx * 13 + (t - 1)) * 32;
                while (__hip_atomic_load((uint32_t*)f, __ATOMIC_RELAXED, __HIP_MEMORY_SCOPE_AGENT) < 32u)
                    __builtin_amdgcn_s_sleep(2);
            }
            __syncthreads();
            const int8_t* zPrev = ZS + (size_t)(t - 1) * ZBYTES + (size_t)mIdx * 8 * 16384;
            run_phase_z<8>(zPrev, wbStrip + (size_t)16 * 12288, sB0, sB1, wave, lane, acc);
        }

        // ---- LIF epilogue (registers): C/D row=(r&3)+8*(r>>2)+4*hl, col=lane32 ----
#pragma unroll
        for (int r = 0; r < 16; ++r) {
#pragma clang fp contract(off)
            // exact digit combine (|counts| < 2^24)
            float cur = (float)acc[2][r] * (1.0f / 512.0f)
                      + (float)acc[1][r] * (1.0f / 131072.0f)
                      + (float)acc[0][r] * (1.0f / 33554432.0f);
            int row = (r & 3) + 8 * (r >> 2) + 4 * hl;    // 0..31 (C/D layout)
            float v_dec = vmem[r] + 0.1f * ((0.0f - vmem[r]) + isyn[r]);
            float i_dec = isyn[r] - 0.2f * isyn[r];
            bool z = (v_dec > 1.0f);
            vmem[r] = z ? 0.0f : v_dec;                   // == (1-z)*v_dec + z*V_RESET exactly
            isyn[r] = i_dec + cur;
            if (t == T_STEPS - 1) {
                int b = mBase + wave * 32 + row;
                int h = nBase + lane32;
                Zbf[(size_t)b * H_DIM + h] = z ? (uint16_t)0x3F80 : (uint16_t)0;
            } else {
                // [group=wave][kk=nt&3][lane'=(lane32>>4)*32+row][j=lane32&15] into sZ
                sZ[wave * 1024 + ((lane32 >> 4) * 32 + row) * 16 + (lane32 & 15)]
                    = z ? (int8_t)1 : (int8_t)0;
            }
        }

        if (t < T_STEPS - 1) {
            __syncthreads();   // sZ complete
            // repack: 16 contiguous bytes/thread -> two 8B agent-scope stores
            const u64* sp = (const u64*)&sZ[tid * 16];
            u64 v0 = sp[0], v1 = sp[1];
            int8_t* dst = ZS + (size_t)t * ZBYTES + ((size_t)mIdx * 8 + (nt >> 2)) * 16384
                        + (tid >> 6) * 4096 + (nt & 3) * 1024 + (tid & 63) * 16;
            __hip_atomic_store((u64*)dst,       v0, __ATOMIC_RELAXED, __HIP_MEMORY_SCOPE_AGENT);
            __hip_atomic_store((u64*)(dst + 8), v1, __ATOMIC_RELAXED, __HIP_MEMORY_SCOPE_AGENT);
            __syncthreads();   // drains vmcnt(0): all 256 threads' z-stores issued & retired
            if (tid == 0)
                __hip_atomic_fetch_add(&cnt[((size_t)mIdx * 13 + t) * 32], 1u,
                                       __ATOMIC_RELEASE, __HIP_MEMORY_SCOPE_AGENT);
        }
    }
}

// ---------- output GEMM: out = z_T @ out_w^T + out_b (bf16x3) ----------
__launch_bounds__(256)
__global__ void out_gemm_kernel(const uint16_t* __restrict__ Zfin,  // [B][H_DIM] bf16
                                const uint16_t* __restrict__ OW3,   // [3][O_DIM][H_DIM] bf16
                                const float* __restrict__ out_b,
                                float* __restrict__ out) {
    __shared__ uint16_t sA[16 * 32];        // 1 KB : [row(16)][k(32)]
    __shared__ uint16_t sB[3][128 * 32];    // 24 KB: [s][row(128)][k(32)]

    const int tid  = threadIdx.x;
    const int wave = tid >> 6, lane = tid & 63;
    const int quad = lane >> 4, col = lane & 15;

    const int mBase = blockIdx.x * 16;

    floatx4 acc[2] = {};

    const int ldRow = lane >> 2;        // 0..15
    const int ldCol = (lane & 3) * 8;   // element offset (x2B = 16B)

    for (int kt = 0; kt < H_DIM / 32; ++kt) {
        const int kb = kt * 32;
        __syncthreads();
        if (wave == 0) {
            const uint16_t* g = Zfin + (size_t)(mBase + ldRow) * H_DIM + kb + ldCol;
            gload_lds16(g, &sA[0]);
        }
#pragma unroll
        for (int s = 0; s < 3; ++s) {
            const uint16_t* wsrc = OW3 + (size_t)s * O_DIM * H_DIM;
#pragma unroll
            for (int j = 0; j < 2; ++j) {
                const int rseg = j * 4 + wave;   // 0..7, 16 rows each
                const uint16_t* g = wsrc + (size_t)(rseg * 16 + ldRow) * H_DIM + kb + ldCol;
                gload_lds16(g, &sB[s][rseg * 16 * 32]);
            }
        }
        __syncthreads();

        bf16x8 aF = *reinterpret_cast<const bf16x8*>(&sA[col * 32 + quad * 8]);
#pragma unroll
        for (int s = 0; s < 3; ++s) {
#pragma unroll
            for (int ni = 0; ni < 2; ++ni) {
                int row = wave * 32 + ni * 16 + col;
                bf16x8 bF = *reinterpret_cast<const bf16x8*>(&sB[s][row * 32 + quad * 8]);
                acc[ni] = __builtin_amdgcn_mfma_f32_16x16x32_bf16(aF, bF, acc[ni], 0, 0, 0);
            }
        }
    }

    {
#pragma clang fp contract(off)
#pragma unroll
        for (int ni = 0; ni < 2; ++ni)
#pragma unroll
            for (int r = 0; r < 4; ++r) {
                int b = mBase + quad * 4 + r;          // C/D: row = quad*4 + reg
                int h = wave * 32 + ni * 16 + col;     //      col = lane&15
                out[(size_t)b * O_DIM + h] = acc[ni][r] + out_b[h];
            }
    }
}

extern "C" void kernel_launch(void* const* d_in, const int* in_sizes, int n_in,
                              void* d_out, int out_size, void* d_ws, size_t ws_size,
                              hipStream_t stream) {
    const float* x     = (const float*)d_in[0];
    const float* w_in  = (const float*)d_in[1];
    const float* w_rec = (const float*)d_in[2];
    const float* out_w = (const float*)d_in[3];
    const float* out_b = (const float*)d_in[4];
    float* out = (float*)d_out;

    char* ws = (char*)d_ws;
    size_t off = 0;
    int8_t*   WB   = (int8_t*)(ws + off);   off += (size_t)3 * H_DIM * K_TOT;        // 9.4 MB
    uint16_t* OW3  = (uint16_t*)(ws + off); off += (size_t)3 * O_DIM * H_DIM * 2;    // 0.8 MB
    int8_t*   Xall = (int8_t*)(ws + off);   off += (size_t)T_STEPS * B_DIM * I_DIM;  // 117 MB
    uint16_t* Zbf  = (uint16_t*)(ws + off); off += (size_t)B_DIM * H_DIM * 2;        // 8 MB
    int8_t*   ZS   = (int8_t*)(ws + off);   off += (size_t)13 * ZBYTES;              // 54.5 MB (per-step z)
    uint32_t* CNT  = (uint32_t*)(ws + off); off += (size_t)32 * 13 * 32 * 4;         // 53 KB

    split_w_kernel<<<(H_DIM * K_TOT) / 256, 256, 0, stream>>>(w_in, w_rec, WB);
    split_ow_kernel<<<(O_DIM * H_DIM) / 256, 256, 0, stream>>>(out_w, OW3);
    cvt_x_kernel<<<(int)(((size_t)T_STEPS * B_DIM * I_DIM / 16) / 256), 256, 0, stream>>>(x, Xall);
    zero_cnt_kernel<<<(32 * 13 * 32) / 256, 256, 0, stream>>>(CNT);

    // PLAIN launch: capture-safe. Co-residency by exact-fit occupancy (see kernel comment).
    lif_persist_kernel<<<dim3(1024), dim3(256), 0, stream>>>(Xall, WB, ZS, Zbf, CNT);

    out_gemm_kernel<<<B_DIM / 16, 256, 0, stream>>>(Zbf, OW3, out_b, out);
}

// Round 5
// 1577.618 us; speedup vs baseline: 1.0875x; 1.0875x over previous
//
#include <hip/hip_runtime.h>
#include <stdint.h>

#define T_STEPS 14
#define B_DIM   4096
#define I_DIM   2048
#define H_DIM   1024
#define O_DIM   128
#define K_TOT   3072   // I_DIM + H_DIM
#define ZBYTES  ((size_t)B_DIM * H_DIM)

// fixed-point scale 2^25: |w|max ~0.16 -> |W| ~5.1M, 3 signed base-256 digits exact
#define WSCALE_F 33554432.0f

typedef __bf16  bf16x8  __attribute__((ext_vector_type(8)));
typedef float   floatx4 __attribute__((ext_vector_type(4)));
typedef int     int4v   __attribute__((ext_vector_type(4)));
typedef int     int16v  __attribute__((ext_vector_type(16)));
typedef unsigned long long u64;

__device__ __forceinline__ uint16_t f2bf_rne(float f) {
    uint32_t u = __float_as_uint(f);
    u += 0x7fffu + ((u >> 16) & 1u);
    return (uint16_t)(u >> 16);
}
__device__ __forceinline__ float bf2f(uint16_t h) {
    return __uint_as_float(((uint32_t)h) << 16);
}

// async global->LDS, 16B/lane; LDS dest = wave-uniform base + lane*16 (implicit)
__device__ __forceinline__ void gload_lds16(const void* g, void* l) {
    __builtin_amdgcn_global_load_lds((__attribute__((address_space(1))) void*)g,
                                     (__attribute__((address_space(3))) void*)l, 16, 0, 0);
}

// ================= fragment-order layouts, BK=128 (validated r11) =================
// B digits: WB[nt(32)][ktw(24)][s(3)][kk(4)][lane(64)][16B]      (12 KB chunks)
// A spikes: Xall[t][mIdx(32)][ktx(16)][group(4)][kk(4)][lane(64)][16B]  (16 KB chunks)
// Z state:  ZS[t][mIdx(32)][ktz(8)][group(4)][kk(4)][lane(64)][16B]     (16 KB chunks)
// element (row = group*32 + (lane&31), k = kt*128 + kk*32 + (lane>>5)*16 + j)

__global__ void split_w_kernel(const float* __restrict__ w_in, const float* __restrict__ w_rec,
                               int8_t* __restrict__ WB) {
    int idx = blockIdx.x * 256 + threadIdx.x;          // over H_DIM*K_TOT
    int h = idx / K_TOT;
    int k = idx - h * K_TOT;
    float w = (k < I_DIM) ? w_in[(size_t)h * I_DIM + k]
                          : w_rec[(size_t)h * H_DIM + (k - I_DIM)];
    int W  = __float2int_rn(w * WSCALE_F);
    int d0 = (int8_t)(W & 0xFF);
    int r1 = (W - d0) >> 8;
    int d1 = (int8_t)(r1 & 0xFF);
    int d2 = (r1 - d1) >> 8;                           // |d2| <= ~80
    int nt = h >> 5, n32 = h & 31;
    int ktw = k >> 7, k128 = k & 127;
    int kk = k128 >> 5, half = (k128 >> 4) & 1, j = k128 & 15;
    int lane = half * 32 + n32;
    size_t base = (size_t)(nt * 24 + ktw) * 12288 + kk * 1024 + lane * 16 + j;
    WB[base] = (int8_t)d0; WB[base + 4096] = (int8_t)d1; WB[base + 8192] = (int8_t)d2;
}

// ---------- out_w -> bf16 hi/mid/lo (validated) ----------
__global__ void split_ow_kernel(const float* __restrict__ out_w, uint16_t* __restrict__ OW3) {
    int idx = blockIdx.x * 256 + threadIdx.x;          // over O_DIM*H_DIM
    float w = out_w[idx];
    uint16_t hi = f2bf_rne(w);
    float r1 = w - bf2f(hi);
    uint16_t mid = f2bf_rne(r1);
    float r2 = r1 - bf2f(mid);
    uint16_t lo = f2bf_rne(r2);
    const size_t S = (size_t)O_DIM * H_DIM;
    OW3[idx] = hi; OW3[idx + S] = mid; OW3[idx + 2 * S] = lo;
}

// ---------- x fp32 -> i8, ALL timesteps, BK=128 fragment-order (validated r11) ----------
__global__ void cvt_x_kernel(const float* __restrict__ x, int8_t* __restrict__ xb) {
    size_t gid = (size_t)blockIdx.x * 256 + threadIdx.x;   // one 16B output granule each
    int g = (int)(gid & 1023);                             // granule within 16KB chunk
    size_t chunk = gid >> 10;                              // (t*32 + mIdx)*16 + kt
    int kt   = (int)(chunk & 15);
    int mIdx = (int)((chunk >> 4) & 31);
    int t    = (int)(chunk >> 9);
    int group = g >> 8, kk = (g >> 6) & 3, lane = g & 63;
    int half = lane >> 5, row32 = lane & 31;
    int b = mIdx * 128 + group * 32 + row32;
    int k = kt * 128 + kk * 32 + half * 16;
    const float4* src = (const float4*)(x + ((size_t)t * B_DIM + b) * I_DIM + k);
    union { int8_t bytes[16]; int4v v; } u;
#pragma unroll
    for (int q = 0; q < 4; ++q) {
        float4 f = src[q];
        u.bytes[q * 4 + 0] = (int8_t)(f.x > 0.5f);
        u.bytes[q * 4 + 1] = (int8_t)(f.y > 0.5f);
        u.bytes[q * 4 + 2] = (int8_t)(f.z > 0.5f);
        u.bytes[q * 4 + 3] = (int8_t)(f.w > 0.5f);
    }
    ((int4v*)xb)[gid] = u.v;
}

// ---------- zero the group-sync counters (32 groups x 13 steps x 128B stride) ----------
// agent-scope stores: zeros reach the coherence point regardless of replay history
__global__ void zero_cnt_kernel(uint32_t* __restrict__ cnt) {
    __hip_atomic_store(&cnt[blockIdx.x * 256 + threadIdx.x], 0u,
                       __ATOMIC_RELAXED, __HIP_MEMORY_SCOPE_AGENT);
}

// ================= pipelined K-step (validated R2/R3) =================
// A fragments: global->VGPR direct (read by one lane of one wave only). B (weights,
// reused 4x/block) double-buffered in LDS with counted vmcnt: per iter the 7 vmem ops
// issued are [A(kt):4][stageB(kt+1):3]; vmcnt(7) drains B(kt) (issued last iter) while
// keeping this iter's loads in flight across the raw s_barrier.
__device__ __forceinline__ void lif_iter(const int8_t* __restrict__ aP,   // A frag: chunk + wave*4096 + lane*16
                                         const int8_t* __restrict__ bPn,  // next B chunk (12KB) or null
                                         const int8_t* cur, int8_t* nxt,  // LDS ping-pong
                                         int wave, int lane, bool stage_next,
                                         int16v (&acc)[3]) {
    int4v a0 = *(const int4v*)(aP);
    int4v a1 = *(const int4v*)(aP + 1024);
    int4v a2 = *(const int4v*)(aP + 2048);
    int4v a3 = *(const int4v*)(aP + 3072);
    __builtin_amdgcn_sched_barrier(0);
    if (stage_next) {
        gload_lds16(bPn + (size_t)wave * 1024 + lane * 16,       nxt + wave * 1024);
        gload_lds16(bPn + (size_t)(4 + wave) * 1024 + lane * 16, nxt + (4 + wave) * 1024);
        gload_lds16(bPn + (size_t)(8 + wave) * 1024 + lane * 16, nxt + (8 + wave) * 1024);
        asm volatile("s_waitcnt vmcnt(7)" ::: "memory");   // drain B(kt); keep A(kt)+B(kt+1) in flight
    } else {
        asm volatile("s_waitcnt vmcnt(4)" ::: "memory");   // last iter: drain B(kt)
    }
    __builtin_amdgcn_s_barrier();                          // all waves' B(kt) landed
    __builtin_amdgcn_sched_barrier(0);
#pragma unroll
    for (int kk = 0; kk < 4; ++kk) {
        int4v aF = (kk == 0) ? a0 : (kk == 1) ? a1 : (kk == 2) ? a2 : a3;
#pragma unroll
        for (int s = 0; s < 3; ++s) {
            int4v bF = *(const int4v*)(cur + s * 4096 + kk * 1024 + lane * 16);
            acc[s] = __builtin_amdgcn_mfma_i32_32x32x32_i8(aF, bF, acc[s], 0, 0, 0);
        }
    }
    asm volatile("s_waitcnt lgkmcnt(0)" ::: "memory");     // reads of 'cur' done
    __builtin_amdgcn_s_barrier();                          // safe to overwrite 'cur' next iter
}

template<int NKT>
__device__ __forceinline__ void run_phase(const int8_t* __restrict__ aChunk0,  // + kt*16384
                                          const int8_t* __restrict__ bChunk0,  // + kt*12288
                                          int8_t* sB0, int8_t* sB1,
                                          int wave, int lane, int16v (&acc)[3]) {
    gload_lds16(bChunk0 + (size_t)wave * 1024 + lane * 16,       sB0 + wave * 1024);
    gload_lds16(bChunk0 + (size_t)(4 + wave) * 1024 + lane * 16, sB0 + (4 + wave) * 1024);
    gload_lds16(bChunk0 + (size_t)(8 + wave) * 1024 + lane * 16, sB0 + (8 + wave) * 1024);
    const int8_t* aW = aChunk0 + wave * 4096 + lane * 16;
#pragma unroll 1
    for (int kt = 0; kt + 2 < NKT; kt += 2) {
        lif_iter(aW + (size_t)kt * 16384,       bChunk0 + (size_t)(kt + 1) * 12288, sB0, sB1, wave, lane, true, acc);
        lif_iter(aW + (size_t)(kt + 1) * 16384, bChunk0 + (size_t)(kt + 2) * 12288, sB1, sB0, wave, lane, true, acc);
    }
    lif_iter(aW + (size_t)(NKT - 2) * 16384, bChunk0 + (size_t)(NKT - 1) * 12288, sB0, sB1, wave, lane, true, acc);
    lif_iter(aW + (size_t)(NKT - 1) * 16384, nullptr,                             sB1, sB0, wave, lane, false, acc);
}

// ================= persistent LIF: all 14 steps, ONE PLAIN launch =================
// PLAIN launch (graph-capture-safe). Co-residency of all 1024 blocks by exact-fit
// capacity: 64 VGPR (<=128 bound), 28KB LDS x4 = 112KB <= 160KB, 16 waves/CU <= 32
// -> 4 blocks/CU x 256 CU = 1024 = grid (validated on HW by R1-R3 coop-launch checks).
// Coherence protocol (R4 post-mortem: agent-scope atomic z LOADS cost +59% kernel time
// by bypassing L2; replaced by textbook release/acquire with CHEAP fences):
//  - producers: z stores as relaxed agent-scope 8B atomics (sc-flagged write-through;
//    vmcnt-0 ack = LLC arrival), __syncthreads drains vmcnt, then RELAXED flag add.
//  - consumers: relaxed spin on flag, __syncthreads, then ONE acquire-agent fence
//    (buffer_inv: clean-line L1/L2 invalidate, no writeback) -> plain CACHED z loads
//    are fresh on first execution (virgin buffer) AND on every graph replay (stale
//    lines from replay N invalidated). Only clean lines exist at fence time (Zbf is
//    written after the last fence), so inv cannot discard data.
//  - W refetch after inv comes from LLC (9.4MB resident), ~2.3MB/XCD/step ≈ 25-40µs
//    total — vs ~400µs the atomic-load path cost in R4.
__launch_bounds__(256, 4)
__global__ void lif_persist_kernel(const int8_t* __restrict__ Xall,
                                   const int8_t* __restrict__ WB,
                                   int8_t* __restrict__ ZS,      // 13 per-step z buffers
                                   uint16_t* __restrict__ Zbf,
                                   uint32_t* __restrict__ cnt) {
    __shared__ int8_t sB0[12288];   // [s(3)][kk(4)][lane(64)][16B]
    __shared__ int8_t sB1[12288];
    __shared__ int8_t sZ[4096];     // z repack staging

    const int tid  = threadIdx.x;
    const int wave = tid >> 6, lane = tid & 63;
    const int lane32 = lane & 31, hl = lane >> 5;

    // 2D parity swizzle (bijective on 0..1023; correctness-independent of XCD mapping)
    const int bid = blockIdx.x;
    const int xs = bid & 7, q = bid >> 3;
    const int mIdx = (xs & 1) * 16 + (q & 15);
    const int nt   = (xs >> 1) * 8 + (q >> 4);

    const int mBase = mIdx * 128, nBase = nt * 32;
    const int8_t* wbStrip = WB + (size_t)nt * 24 * 12288;

    float vmem[16], isyn[16];
#pragma unroll
    for (int r = 0; r < 16; ++r) { vmem[r] = 0.0f; isyn[r] = 0.0f; }

    for (int t = 0; t < T_STEPS; ++t) {
        int16v acc[3] = {};

        // ---- X phase: kt 0..15 (no dependence on z(t-1)) ----
        const int8_t* Xt = Xall + (size_t)t * ((size_t)B_DIM * I_DIM) + (size_t)mIdx * 16 * 16384;
        run_phase<16>(Xt, wbStrip, sB0, sB1, wave, lane, acc);

        // ---- recurrent phase: needs z(t-1) from the 32 blocks of this mIdx group ----
        if (t > 0) {
            if (tid == 0) {
                const uint32_t* f = cnt + ((size_t)mIdx * 13 + (t - 1)) * 32;
                while (__hip_atomic_load((uint32_t*)f, __ATOMIC_RELAXED, __HIP_MEMORY_SCOPE_AGENT) < 32u)
                    __builtin_amdgcn_s_sleep(2);
            }
            __syncthreads();
            // acquire: invalidate clean L1/L2 lines so plain loads below see LLC data
            // (first-execution virginity + replay staleness both covered)
            __builtin_amdgcn_fence(__ATOMIC_ACQUIRE, "agent");
            const int8_t* zPrev = ZS + (size_t)(t - 1) * ZBYTES + (size_t)mIdx * 8 * 16384;
            run_phase<8>(zPrev, wbStrip + (size_t)16 * 12288, sB0, sB1, wave, lane, acc);
        }

        // ---- LIF epilogue (registers): C/D row=(r&3)+8*(r>>2)+4*hl, col=lane32 ----
#pragma unroll
        for (int r = 0; r < 16; ++r) {
#pragma clang fp contract(off)
            // exact digit combine (|counts| < 2^24)
            float cur = (float)acc[2][r] * (1.0f / 512.0f)
                      + (float)acc[1][r] * (1.0f / 131072.0f)
                      + (float)acc[0][r] * (1.0f / 33554432.0f);
            int row = (r & 3) + 8 * (r >> 2) + 4 * hl;    // 0..31 (C/D layout)
            float v_dec = vmem[r] + 0.1f * ((0.0f - vmem[r]) + isyn[r]);
            float i_dec = isyn[r] - 0.2f * isyn[r];
            bool z = (v_dec > 1.0f);
            vmem[r] = z ? 0.0f : v_dec;                   // == (1-z)*v_dec + z*V_RESET exactly
            isyn[r] = i_dec + cur;
            if (t == T_STEPS - 1) {
                int b = mBase + wave * 32 + row;
                int h = nBase + lane32;
                Zbf[(size_t)b * H_DIM + h] = z ? (uint16_t)0x3F80 : (uint16_t)0;
            } else {
                // [group=wave][kk=nt&3][lane'=(lane32>>4)*32+row][j=lane32&15] into sZ
                sZ[wave * 1024 + ((lane32 >> 4) * 32 + row) * 16 + (lane32 & 15)]
                    = z ? (int8_t)1 : (int8_t)0;
            }
        }

        if (t < T_STEPS - 1) {
            __syncthreads();   // sZ complete
            // repack: 16 contiguous bytes/thread -> two 8B agent-scope stores
            const u64* sp = (const u64*)&sZ[tid * 16];
            u64 v0 = sp[0], v1 = sp[1];
            int8_t* dst = ZS + (size_t)t * ZBYTES + ((size_t)mIdx * 8 + (nt >> 2)) * 16384
                        + (tid >> 6) * 4096 + (nt & 3) * 1024 + (tid & 63) * 16;
            __hip_atomic_store((u64*)dst,       v0, __ATOMIC_RELAXED, __HIP_MEMORY_SCOPE_AGENT);
            __hip_atomic_store((u64*)(dst + 8), v1, __ATOMIC_RELAXED, __HIP_MEMORY_SCOPE_AGENT);
            __syncthreads();   // drains vmcnt(0): all z-stores acked at the coherence point
            if (tid == 0)
                __hip_atomic_fetch_add(&cnt[((size_t)mIdx * 13 + t) * 32], 1u,
                                       __ATOMIC_RELAXED, __HIP_MEMORY_SCOPE_AGENT);
        }
    }
}

// ---------- output GEMM: out = z_T @ out_w^T + out_b (bf16x3) ----------
__launch_bounds__(256)
__global__ void out_gemm_kernel(const uint16_t* __restrict__ Zfin,  // [B][H_DIM] bf16
                                const uint16_t* __restrict__ OW3,   // [3][O_DIM][H_DIM] bf16
                                const float* __restrict__ out_b,
                                float* __restrict__ out) {
    __shared__ uint16_t sA[16 * 32];        // 1 KB : [row(16)][k(32)]
    __shared__ uint16_t sB[3][128 * 32];    // 24 KB: [s][row(128)][k(32)]

    const int tid  = threadIdx.x;
    const int wave = tid >> 6, lane = tid & 63;
    const int quad = lane >> 4, col = lane & 15;

    const int mBase = blockIdx.x * 16;

    floatx4 acc[2] = {};

    const int ldRow = lane >> 2;        // 0..15
    const int ldCol = (lane & 3) * 8;   // element offset (x2B = 16B)

    for (int kt = 0; kt < H_DIM / 32; ++kt) {
        const int kb = kt * 32;
        __syncthreads();
        if (wave == 0) {
            const uint16_t* g = Zfin + (size_t)(mBase + ldRow) * H_DIM + kb + ldCol;
            gload_lds16(g, &sA[0]);
        }
#pragma unroll
        for (int s = 0; s < 3; ++s) {
            const uint16_t* wsrc = OW3 + (size_t)s * O_DIM * H_DIM;
#pragma unroll
            for (int j = 0; j < 2; ++j) {
                const int rseg = j * 4 + wave;   // 0..7, 16 rows each
                const uint16_t* g = wsrc + (size_t)(rseg * 16 + ldRow) * H_DIM + kb + ldCol;
                gload_lds16(g, &sB[s][rseg * 16 * 32]);
            }
        }
        __syncthreads();

        bf16x8 aF = *reinterpret_cast<const bf16x8*>(&sA[col * 32 + quad * 8]);
#pragma unroll
        for (int s = 0; s < 3; ++s) {
#pragma unroll
            for (int ni = 0; ni < 2; ++ni) {
                int row = wave * 32 + ni * 16 + col;
                bf16x8 bF = *reinterpret_cast<const bf16x8*>(&sB[s][row * 32 + quad * 8]);
                acc[ni] = __builtin_amdgcn_mfma_f32_16x16x32_bf16(aF, bF, acc[ni], 0, 0, 0);
            }
        }
    }

    {
#pragma clang fp contract(off)
#pragma unroll
        for (int ni = 0; ni < 2; ++ni)
#pragma unroll
            for (int r = 0; r < 4; ++r) {
                int b = mBase + quad * 4 + r;          // C/D: row = quad*4 + reg
                int h = wave * 32 + ni * 16 + col;     //      col = lane&15
                out[(size_t)b * O_DIM + h] = acc[ni][r] + out_b[h];
            }
    }
}

extern "C" void kernel_launch(void* const* d_in, const int* in_sizes, int n_in,
                              void* d_out, int out_size, void* d_ws, size_t ws_size,
                              hipStream_t stream) {
    const float* x     = (const float*)d_in[0];
    const float* w_in  = (const float*)d_in[1];
    const float* w_rec = (const float*)d_in[2];
    const float* out_w = (const float*)d_in[3];
    const float* out_b = (const float*)d_in[4];
    float* out = (float*)d_out;

    char* ws = (char*)d_ws;
    size_t off = 0;
    int8_t*   WB   = (int8_t*)(ws + off);   off += (size_t)3 * H_DIM * K_TOT;        // 9.4 MB
    uint16_t* OW3  = (uint16_t*)(ws + off); off += (size_t)3 * O_DIM * H_DIM * 2;    // 0.8 MB
    int8_t*   Xall = (int8_t*)(ws + off);   off += (size_t)T_STEPS * B_DIM * I_DIM;  // 117 MB
    uint16_t* Zbf  = (uint16_t*)(ws + off); off += (size_t)B_DIM * H_DIM * 2;        // 8 MB
    int8_t*   ZS   = (int8_t*)(ws + off);   off += (size_t)13 * ZBYTES;              // 54.5 MB (per-step z)
    uint32_t* CNT  = (uint32_t*)(ws + off); off += (size_t)32 * 13 * 32 * 4;         // 53 KB

    split_w_kernel<<<(H_DIM * K_TOT) / 256, 256, 0, stream>>>(w_in, w_rec, WB);
    split_ow_kernel<<<(O_DIM * H_DIM) / 256, 256, 0, stream>>>(out_w, OW3);
    cvt_x_kernel<<<(int)(((size_t)T_STEPS * B_DIM * I_DIM / 16) / 256), 256, 0, stream>>>(x, Xall);
    zero_cnt_kernel<<<(32 * 13 * 32) / 256, 256, 0, stream>>>(CNT);

    // PLAIN launch: capture-safe. Co-residency by exact-fit occupancy (see kernel comment).
    lif_persist_kernel<<<dim3(1024), dim3(256), 0, stream>>>(Xall, WB, ZS, Zbf, CNT);

    out_gemm_kernel<<<B_DIM / 16, 256, 0, stream>>>(Zbf, OW3, out_b, out);
}

// Round 6
// 1295.678 us; speedup vs baseline: 1.3241x; 1.2176x over previous
//
#include <hip/hip_runtime.h>
#include <stdint.h>

#define T_STEPS 14
#define B_DIM   4096
#define I_DIM   2048
#define H_DIM   1024
#define O_DIM   128
#define K_TOT   3072   // I_DIM + H_DIM
#define ZBYTES  ((size_t)B_DIM * H_DIM)

// fixed-point scale 2^25: |w|max ~0.16 -> |W| ~5.1M, 3 signed base-256 digits exact
#define WSCALE_F 33554432.0f

typedef __bf16  bf16x8  __attribute__((ext_vector_type(8)));
typedef float   floatx4 __attribute__((ext_vector_type(4)));
typedef int     int4v   __attribute__((ext_vector_type(4)));
typedef int     int16v  __attribute__((ext_vector_type(16)));
typedef unsigned long long u64;

__device__ __forceinline__ uint16_t f2bf_rne(float f) {
    uint32_t u = __float_as_uint(f);
    u += 0x7fffu + ((u >> 16) & 1u);
    return (uint16_t)(u >> 16);
}
__device__ __forceinline__ float bf2f(uint16_t h) {
    return __uint_as_float(((uint32_t)h) << 16);
}

// async global->LDS, 16B/lane; LDS dest = wave-uniform base + lane*16 (implicit)
__device__ __forceinline__ void gload_lds16(const void* g, void* l) {
    __builtin_amdgcn_global_load_lds((__attribute__((address_space(1))) void*)g,
                                     (__attribute__((address_space(3))) void*)l, 16, 0, 0);
}

// ================= fragment-order layouts, BK=128 (validated r11) =================
// B digits: WB[nt(32)][ktw(24)][s(3)][kk(4)][lane(64)][16B]      (12 KB chunks)
// A spikes: Xall[t][mIdx(32)][ktx(16)][group(4)][kk(4)][lane(64)][16B]  (16 KB chunks)
// Z state:  ZS[t][mIdx(32)][ktz(8)][group(4)][kk(4)][lane(64)][16B]     (16 KB chunks)
// element (row = group*32 + (lane&31), k = kt*128 + kk*32 + (lane>>5)*16 + j)

__global__ void split_w_kernel(const float* __restrict__ w_in, const float* __restrict__ w_rec,
                               int8_t* __restrict__ WB) {
    int idx = blockIdx.x * 256 + threadIdx.x;          // over H_DIM*K_TOT
    int h = idx / K_TOT;
    int k = idx - h * K_TOT;
    float w = (k < I_DIM) ? w_in[(size_t)h * I_DIM + k]
                          : w_rec[(size_t)h * H_DIM + (k - I_DIM)];
    int W  = __float2int_rn(w * WSCALE_F);
    int d0 = (int8_t)(W & 0xFF);
    int r1 = (W - d0) >> 8;
    int d1 = (int8_t)(r1 & 0xFF);
    int d2 = (r1 - d1) >> 8;                           // |d2| <= ~80
    int nt = h >> 5, n32 = h & 31;
    int ktw = k >> 7, k128 = k & 127;
    int kk = k128 >> 5, half = (k128 >> 4) & 1, j = k128 & 15;
    int lane = half * 32 + n32;
    size_t base = (size_t)(nt * 24 + ktw) * 12288 + kk * 1024 + lane * 16 + j;
    WB[base] = (int8_t)d0; WB[base + 4096] = (int8_t)d1; WB[base + 8192] = (int8_t)d2;
}

// ---------- out_w -> bf16 hi/mid/lo (validated) ----------
__global__ void split_ow_kernel(const float* __restrict__ out_w, uint16_t* __restrict__ OW3) {
    int idx = blockIdx.x * 256 + threadIdx.x;          // over O_DIM*H_DIM
    float w = out_w[idx];
    uint16_t hi = f2bf_rne(w);
    float r1 = w - bf2f(hi);
    uint16_t mid = f2bf_rne(r1);
    float r2 = r1 - bf2f(mid);
    uint16_t lo = f2bf_rne(r2);
    const size_t S = (size_t)O_DIM * H_DIM;
    OW3[idx] = hi; OW3[idx + S] = mid; OW3[idx + 2 * S] = lo;
}

// ---------- x fp32 -> i8, ALL timesteps, BK=128 fragment-order (validated r11) ----------
__global__ void cvt_x_kernel(const float* __restrict__ x, int8_t* __restrict__ xb) {
    size_t gid = (size_t)blockIdx.x * 256 + threadIdx.x;   // one 16B output granule each
    int g = (int)(gid & 1023);                             // granule within 16KB chunk
    size_t chunk = gid >> 10;                              // (t*32 + mIdx)*16 + kt
    int kt   = (int)(chunk & 15);
    int mIdx = (int)((chunk >> 4) & 31);
    int t    = (int)(chunk >> 9);
    int group = g >> 8, kk = (g >> 6) & 3, lane = g & 63;
    int half = lane >> 5, row32 = lane & 31;
    int b = mIdx * 128 + group * 32 + row32;
    int k = kt * 128 + kk * 32 + half * 16;
    const float4* src = (const float4*)(x + ((size_t)t * B_DIM + b) * I_DIM + k);
    union { int8_t bytes[16]; int4v v; } u;
#pragma unroll
    for (int q = 0; q < 4; ++q) {
        float4 f = src[q];
        u.bytes[q * 4 + 0] = (int8_t)(f.x > 0.5f);
        u.bytes[q * 4 + 1] = (int8_t)(f.y > 0.5f);
        u.bytes[q * 4 + 2] = (int8_t)(f.z > 0.5f);
        u.bytes[q * 4 + 3] = (int8_t)(f.w > 0.5f);
    }
    ((int4v*)xb)[gid] = u.v;
}

// ---------- zero the group-sync counters (32 groups x 13 steps x 128B stride) ----------
// agent-scope stores: zeros reach the coherence point regardless of replay history
__global__ void zero_cnt_kernel(uint32_t* __restrict__ cnt) {
    __hip_atomic_store(&cnt[blockIdx.x * 256 + threadIdx.x], 0u,
                       __ATOMIC_RELAXED, __HIP_MEMORY_SCOPE_AGENT);
}

// ================= pipelined K-step (validated R2/R3) =================
// A fragments: global->VGPR direct (read by one lane of one wave only). B (weights,
// reused 4x/block) double-buffered in LDS with counted vmcnt: per iter the 7 vmem ops
// issued are [A(kt):4][stageB(kt+1):3]; vmcnt(7) drains B(kt) (issued last iter) while
// keeping this iter's loads in flight across the raw s_barrier.
__device__ __forceinline__ void lif_iter(const int8_t* __restrict__ aP,   // A frag: chunk + wave*4096 + lane*16
                                         const int8_t* __restrict__ bPn,  // next B chunk (12KB) or null
                                         const int8_t* cur, int8_t* nxt,  // LDS ping-pong
                                         int wave, int lane, bool stage_next,
                                         int16v (&acc)[3]) {
    int4v a0 = *(const int4v*)(aP);
    int4v a1 = *(const int4v*)(aP + 1024);
    int4v a2 = *(const int4v*)(aP + 2048);
    int4v a3 = *(const int4v*)(aP + 3072);
    __builtin_amdgcn_sched_barrier(0);
    if (stage_next) {
        gload_lds16(bPn + (size_t)wave * 1024 + lane * 16,       nxt + wave * 1024);
        gload_lds16(bPn + (size_t)(4 + wave) * 1024 + lane * 16, nxt + (4 + wave) * 1024);
        gload_lds16(bPn + (size_t)(8 + wave) * 1024 + lane * 16, nxt + (8 + wave) * 1024);
        asm volatile("s_waitcnt vmcnt(7)" ::: "memory");   // drain B(kt); keep A(kt)+B(kt+1) in flight
    } else {
        asm volatile("s_waitcnt vmcnt(4)" ::: "memory");   // last iter: drain B(kt)
    }
    __builtin_amdgcn_s_barrier();                          // all waves' B(kt) landed
    __builtin_amdgcn_sched_barrier(0);
#pragma unroll
    for (int kk = 0; kk < 4; ++kk) {
        int4v aF = (kk == 0) ? a0 : (kk == 1) ? a1 : (kk == 2) ? a2 : a3;
#pragma unroll
        for (int s = 0; s < 3; ++s) {
            int4v bF = *(const int4v*)(cur + s * 4096 + kk * 1024 + lane * 16);
            acc[s] = __builtin_amdgcn_mfma_i32_32x32x32_i8(aF, bF, acc[s], 0, 0, 0);
        }
    }
    asm volatile("s_waitcnt lgkmcnt(0)" ::: "memory");     // reads of 'cur' done
    __builtin_amdgcn_s_barrier();                          // safe to overwrite 'cur' next iter
}

__device__ __forceinline__ void stage_b0(const int8_t* __restrict__ bChunk0,
                                         int8_t* sB0, int wave, int lane) {
    gload_lds16(bChunk0 + (size_t)wave * 1024 + lane * 16,       sB0 + wave * 1024);
    gload_lds16(bChunk0 + (size_t)(4 + wave) * 1024 + lane * 16, sB0 + (4 + wave) * 1024);
    gload_lds16(bChunk0 + (size_t)(8 + wave) * 1024 + lane * 16, sB0 + (8 + wave) * 1024);
}

// PRESTAGED: B(0) already staged into sB0 by the caller (e.g. before a flag spin, to
// hide the load latency). vmcnt math unchanged: first iter sees <=10 outstanding and
// vmcnt(7) drains exactly the B(0) loads (counted waits are upper bounds).
template<int NKT, bool PRESTAGED>
__device__ __forceinline__ void run_phase(const int8_t* __restrict__ aChunk0,  // + kt*16384
                                          const int8_t* __restrict__ bChunk0,  // + kt*12288
                                          int8_t* sB0, int8_t* sB1,
                                          int wave, int lane, int16v (&acc)[3]) {
    if constexpr (!PRESTAGED) {
        stage_b0(bChunk0, sB0, wave, lane);
    }
    const int8_t* aW = aChunk0 + wave * 4096 + lane * 16;
#pragma unroll 1
    for (int kt = 0; kt + 2 < NKT; kt += 2) {
        lif_iter(aW + (size_t)kt * 16384,       bChunk0 + (size_t)(kt + 1) * 12288, sB0, sB1, wave, lane, true, acc);
        lif_iter(aW + (size_t)(kt + 1) * 16384, bChunk0 + (size_t)(kt + 2) * 12288, sB1, sB0, wave, lane, true, acc);
    }
    lif_iter(aW + (size_t)(NKT - 2) * 16384, bChunk0 + (size_t)(NKT - 1) * 12288, sB0, sB1, wave, lane, true, acc);
    lif_iter(aW + (size_t)(NKT - 1) * 16384, nullptr,                             sB1, sB0, wave, lane, false, acc);
}

// ================= persistent LIF: all 14 steps, ONE PLAIN launch =================
// PLAIN launch (graph-capture-safe). Co-residency of all 1024 blocks by exact-fit
// capacity: 64 VGPR (<=128 bound), 28KB LDS x4 = 112KB <= 160KB, 16 waves/CU <= 32
// -> 4 blocks/CU x 256 CU = 1024 = grid (validated on HW by R1-R3 coop-launch checks).
//
// Coherence protocol — NO per-step fence (R5 post-mortem: per-block buffer_inv
// continuously wiped XCD L2s -> staging misses cost ~300us):
//  - Replay staleness: every dispatch boundary performs L2 writeback+invalidate
//    (DIRECT EVIDENCE: the R0 fallback passes with plain dirty-L2 stores read by the
//    next kernel across XCDs under graph replay — impossible without boundary cache
//    maintenance). So no ZS line can survive from replay N into replay N+1's dispatch.
//  - Within one execution: ZS[t] is virgin until producers' agent-scope 8B atomic
//    stores (write-through to LLC, vmcnt-acked before the flag add) land; no block
//    touches those addresses before its flag-spin + __syncthreads (full compiler
//    barrier). Hence plain CACHED consumer loads observe fresh data and keep full
//    L1/L2 reuse (8 consumer blocks per XCD share each z chunk).
//  - Flag spin: relaxed agent-scope atomic loads (LLC-direct, no invalidates ->
//    W stays L2-resident, mIdx groups drift freely; no lockstep miss storms).
__launch_bounds__(256, 4)
__global__ void lif_persist_kernel(const int8_t* __restrict__ Xall,
                                   const int8_t* __restrict__ WB,
                                   int8_t* __restrict__ ZS,      // 13 per-step z buffers
                                   uint16_t* __restrict__ Zbf,
                                   uint32_t* __restrict__ cnt) {
    __shared__ int8_t sB0[12288];   // [s(3)][kk(4)][lane(64)][16B]
    __shared__ int8_t sB1[12288];
    __shared__ int8_t sZ[4096];     // z repack staging

    const int tid  = threadIdx.x;
    const int wave = tid >> 6, lane = tid & 63;
    const int lane32 = lane & 31, hl = lane >> 5;

    // 2D parity swizzle (bijective on 0..1023; correctness-independent of XCD mapping)
    const int bid = blockIdx.x;
    const int xs = bid & 7, q = bid >> 3;
    const int mIdx = (xs & 1) * 16 + (q & 15);
    const int nt   = (xs >> 1) * 8 + (q >> 4);

    const int mBase = mIdx * 128, nBase = nt * 32;
    const int8_t* wbStrip = WB + (size_t)nt * 24 * 12288;

    float vmem[16], isyn[16];
#pragma unroll
    for (int r = 0; r < 16; ++r) { vmem[r] = 0.0f; isyn[r] = 0.0f; }

    for (int t = 0; t < T_STEPS; ++t) {
        int16v acc[3] = {};

        // ---- X phase: kt 0..15 (no dependence on z(t-1)) ----
        const int8_t* Xt = Xall + (size_t)t * ((size_t)B_DIM * I_DIM) + (size_t)mIdx * 16 * 16384;
        run_phase<16, false>(Xt, wbStrip, sB0, sB1, wave, lane, acc);

        // ---- recurrent phase: needs z(t-1) from the 32 blocks of this mIdx group ----
        if (t > 0) {
            const int8_t* zbChunk = wbStrip + (size_t)16 * 12288;
            // prestage z-phase B(0): W doesn't depend on z; load latency hides under spin
            stage_b0(zbChunk, sB0, wave, lane);
            if (tid == 0) {
                const uint32_t* f = cnt + ((size_t)mIdx * 13 + (t - 1)) * 32;
                while (__hip_atomic_load((uint32_t*)f, __ATOMIC_RELAXED, __HIP_MEMORY_SCOPE_AGENT) < 32u)
                    __builtin_amdgcn_s_sleep(2);
            }
            __syncthreads();   // spin result visible to all; also full compiler barrier
            const int8_t* zPrev = ZS + (size_t)(t - 1) * ZBYTES + (size_t)mIdx * 8 * 16384;
            run_phase<8, true>(zPrev, zbChunk, sB0, sB1, wave, lane, acc);
        }

        // ---- LIF epilogue (registers): C/D row=(r&3)+8*(r>>2)+4*hl, col=lane32 ----
#pragma unroll
        for (int r = 0; r < 16; ++r) {
#pragma clang fp contract(off)
            // exact digit combine (|counts| < 2^24)
            float cur = (float)acc[2][r] * (1.0f / 512.0f)
                      + (float)acc[1][r] * (1.0f / 131072.0f)
                      + (float)acc[0][r] * (1.0f / 33554432.0f);
            int row = (r & 3) + 8 * (r >> 2) + 4 * hl;    // 0..31 (C/D layout)
            float v_dec = vmem[r] + 0.1f * ((0.0f - vmem[r]) + isyn[r]);
            float i_dec = isyn[r] - 0.2f * isyn[r];
            bool z = (v_dec > 1.0f);
            vmem[r] = z ? 0.0f : v_dec;                   // == (1-z)*v_dec + z*V_RESET exactly
            isyn[r] = i_dec + cur;
            if (t == T_STEPS - 1) {
                int b = mBase + wave * 32 + row;
                int h = nBase + lane32;
                Zbf[(size_t)b * H_DIM + h] = z ? (uint16_t)0x3F80 : (uint16_t)0;
            } else {
                // [group=wave][kk=nt&3][lane'=(lane32>>4)*32+row][j=lane32&15] into sZ
                sZ[wave * 1024 + ((lane32 >> 4) * 32 + row) * 16 + (lane32 & 15)]
                    = z ? (int8_t)1 : (int8_t)0;
            }
        }

        if (t < T_STEPS - 1) {
            __syncthreads();   // sZ complete
            // repack: 16 contiguous bytes/thread -> two 8B agent-scope stores
            const u64* sp = (const u64*)&sZ[tid * 16];
            u64 v0 = sp[0], v1 = sp[1];
            int8_t* dst = ZS + (size_t)t * ZBYTES + ((size_t)mIdx * 8 + (nt >> 2)) * 16384
                        + (tid >> 6) * 4096 + (nt & 3) * 1024 + (tid & 63) * 16;
            __hip_atomic_store((u64*)dst,       v0, __ATOMIC_RELAXED, __HIP_MEMORY_SCOPE_AGENT);
            __hip_atomic_store((u64*)(dst + 8), v1, __ATOMIC_RELAXED, __HIP_MEMORY_SCOPE_AGENT);
            __syncthreads();   // drains vmcnt(0): all z-stores acked at the coherence point
            if (tid == 0)
                __hip_atomic_fetch_add(&cnt[((size_t)mIdx * 13 + t) * 32], 1u,
                                       __ATOMIC_RELAXED, __HIP_MEMORY_SCOPE_AGENT);
        }
    }
}

// ---------- output GEMM: out = z_T @ out_w^T + out_b (bf16x3) ----------
__launch_bounds__(256)
__global__ void out_gemm_kernel(const uint16_t* __restrict__ Zfin,  // [B][H_DIM] bf16
                                const uint16_t* __restrict__ OW3,   // [3][O_DIM][H_DIM] bf16
                                const float* __restrict__ out_b,
                                float* __restrict__ out) {
    __shared__ uint16_t sA[16 * 32];        // 1 KB : [row(16)][k(32)]
    __shared__ uint16_t sB[3][128 * 32];    // 24 KB: [s][row(128)][k(32)]

    const int tid  = threadIdx.x;
    const int wave = tid >> 6, lane = tid & 63;
    const int quad = lane >> 4, col = lane & 15;

    const int mBase = blockIdx.x * 16;

    floatx4 acc[2] = {};

    const int ldRow = lane >> 2;        // 0..15
    const int ldCol = (lane & 3) * 8;   // element offset (x2B = 16B)

    for (int kt = 0; kt < H_DIM / 32; ++kt) {
        const int kb = kt * 32;
        __syncthreads();
        if (wave == 0) {
            const uint16_t* g = Zfin + (size_t)(mBase + ldRow) * H_DIM + kb + ldCol;
            gload_lds16(g, &sA[0]);
        }
#pragma unroll
        for (int s = 0; s < 3; ++s) {
            const uint16_t* wsrc = OW3 + (size_t)s * O_DIM * H_DIM;
#pragma unroll
            for (int j = 0; j < 2; ++j) {
                const int rseg = j * 4 + wave;   // 0..7, 16 rows each
                const uint16_t* g = wsrc + (size_t)(rseg * 16 + ldRow) * H_DIM + kb + ldCol;
                gload_lds16(g, &sB[s][rseg * 16 * 32]);
            }
        }
        __syncthreads();

        bf16x8 aF = *reinterpret_cast<const bf16x8*>(&sA[col * 32 + quad * 8]);
#pragma unroll
        for (int s = 0; s < 3; ++s) {
#pragma unroll
            for (int ni = 0; ni < 2; ++ni) {
                int row = wave * 32 + ni * 16 + col;
                bf16x8 bF = *reinterpret_cast<const bf16x8*>(&sB[s][row * 32 + quad * 8]);
                acc[ni] = __builtin_amdgcn_mfma_f32_16x16x32_bf16(aF, bF, acc[ni], 0, 0, 0);
            }
        }
    }

    {
#pragma clang fp contract(off)
#pragma unroll
        for (int ni = 0; ni < 2; ++ni)
#pragma unroll
            for (int r = 0; r < 4; ++r) {
                int b = mBase + quad * 4 + r;          // C/D: row = quad*4 + reg
                int h = wave * 32 + ni * 16 + col;     //      col = lane&15
                out[(size_t)b * O_DIM + h] = acc[ni][r] + out_b[h];
            }
    }
}

extern "C" void kernel_launch(void* const* d_in, const int* in_sizes, int n_in,
                              void* d_out, int out_size, void* d_ws, size_t ws_size,
                              hipStream_t stream) {
    const float* x     = (const float*)d_in[0];
    const float* w_in  = (const float*)d_in[1];
    const float* w_rec = (const float*)d_in[2];
    const float* out_w = (const float*)d_in[3];
    const float* out_b = (const float*)d_in[4];
    float* out = (float*)d_out;

    char* ws = (char*)d_ws;
    size_t off = 0;
    int8_t*   WB   = (int8_t*)(ws + off);   off += (size_t)3 * H_DIM * K_TOT;        // 9.4 MB
    uint16_t* OW3  = (uint16_t*)(ws + off); off += (size_t)3 * O_DIM * H_DIM * 2;    // 0.8 MB
    int8_t*   Xall = (int8_t*)(ws + off);   off += (size_t)T_STEPS * B_DIM * I_DIM;  // 117 MB
    uint16_t* Zbf  = (uint16_t*)(ws + off); off += (size_t)B_DIM * H_DIM * 2;        // 8 MB
    int8_t*   ZS   = (int8_t*)(ws + off);   off += (size_t)13 * ZBYTES;              // 54.5 MB (per-step z)
    uint32_t* CNT  = (uint32_t*)(ws + off); off += (size_t)32 * 13 * 32 * 4;         // 53 KB

    split_w_kernel<<<(H_DIM * K_TOT) / 256, 256, 0, stream>>>(w_in, w_rec, WB);
    split_ow_kernel<<<(O_DIM * H_DIM) / 256, 256, 0, stream>>>(out_w, OW3);
    cvt_x_kernel<<<(int)(((size_t)T_STEPS * B_DIM * I_DIM / 16) / 256), 256, 0, stream>>>(x, Xall);
    zero_cnt_kernel<<<(32 * 13 * 32) / 256, 256, 0, stream>>>(CNT);

    // PLAIN launch: capture-safe. Co-residency by exact-fit occupancy (see kernel comment).
    lif_persist_kernel<<<dim3(1024), dim3(256), 0, stream>>>(Xall, WB, ZS, Zbf, CNT);

    out_gemm_kernel<<<B_DIM / 16, 256, 0, stream>>>(Zbf, OW3, out_b, out);
}